// Round 22
// baseline (387.952 us; speedup 1.0000x reference)
//
#include <hip/hip_runtime.h>

#define HH 96
#define WW 96
#define HW 9216
#define NPIX 18432      // B*H*W, B=2
#define OMC 216
#define PP 9604         // 98*98 padded image

typedef __attribute__((ext_vector_type(8))) short short8x;       // MFMA bf16 frag
typedef __attribute__((ext_vector_type(8))) unsigned short ushort8x;
typedef __attribute__((ext_vector_type(4))) float f32x4;

__device__ __forceinline__ f32x4 mfma16(short8x a, short8x b, f32x4 c) {
    return __builtin_amdgcn_mfma_f32_16x16x32_bf16(a, b, c, 0, 0, 0);
}
__device__ __forceinline__ unsigned short f2bf(float f) {
    unsigned int u = __float_as_uint(f);
    u = (u + 0x7FFFu + ((u >> 16) & 1u)) >> 16;   // RNE (finite values)
    return (unsigned short)u;
}
__device__ __forceinline__ float bf2f(unsigned short b) {
    return __uint_as_float((unsigned int)b << 16);
}
__device__ __forceinline__ void split2(float v, unsigned short& h, unsigned short& l) {
    h = f2bf(v);
    l = f2bf(v - bf2f(h));
}
__device__ __forceinline__ void gld_lds16(const unsigned short* src, unsigned short* dst) {
    __builtin_amdgcn_global_load_lds(
        (const __attribute__((address_space(1))) unsigned int*)src,
        (__attribute__((address_space(3))) unsigned int*)dst, 16, 0, 0);
}

// ---------------------------------------------------------------------------
// Zero the 1-px border of the padded activation buffers. Fully parallel:
// one 16B store per thread (776 border px x 128 stores = 99328 items).
__global__ __launch_bounds__(256) void zero_borders(
    unsigned short* __restrict__ diffb,   // [2][98][98][256]
    unsigned short* __restrict__ t1,      // [2][98][98][256]
    unsigned short* __restrict__ catb)    // [2][98][98][512]
{
    int idx = blockIdx.x * 256 + threadIdx.x;
    if (idx >= 99328) return;
    int i = idx >> 7, sub = idx & 127;
    int b = i / 388, r = i % 388;
    int y, x;
    if      (r < 98)  { y = 0;           x = r; }
    else if (r < 196) { y = 97;          x = r - 98; }
    else if (r < 292) { y = r - 196 + 1; x = 0; }
    else              { y = r - 292 + 1; x = 97; }
    size_t P = (size_t)b * PP + (size_t)y * 98 + x;
    ushort8x z = {};
    if (sub < 32)      *(ushort8x*)&diffb[P * 256 + sub * 8] = z;
    else if (sub < 64) *(ushort8x*)&t1[P * 256 + (sub - 32) * 8] = z;
    else               *(ushort8x*)&catb[P * 512 + (sub - 64) * 8] = z;
}

// ---------------------------------------------------------------------------
// NCHW fp32 -> r1b (bf16 NHWC, gather src), diff=R1-Q0 (hi/lo bf16, padded),
// Q0 -> padded cat channels (hi 128..255, lo 384..511). 64 pixels per block.
__global__ __launch_bounds__(256) void prep_acts(
    const float* __restrict__ R1, const float* __restrict__ Q0,
    unsigned short* __restrict__ r1b,    // [NPIX][128] bf16
    unsigned short* __restrict__ diffb,  // [2][98][98][256] hi|lo
    unsigned short* __restrict__ cat)    // [2][98][98][512]
{
    __shared__ float tR[128][64];
    __shared__ float tQ[128][64];
    int tid = threadIdx.x;
    int p0  = blockIdx.x * 64;
    int b   = p0 / HW;
    int rem0 = p0 % HW;

    for (int e = tid; e < 2048; e += 256) {          // 128 ch x 16 float4
        int c = e >> 4, j = e & 15;
        size_t base = ((size_t)(b * 128 + c)) * HW + rem0;
        *(float4*)&tR[c][j * 4] = *(const float4*)(R1 + base + j * 4);
        *(float4*)&tQ[c][j * 4] = *(const float4*)(Q0 + base + j * 4);
    }
    __syncthreads();

    int p = tid & 63, half = tid >> 6;   // half 0..3
    int c0 = half * 32;
    int pix = p0 + p;
    int rm = pix % HW, yy = rm / 96, xx = rm % 96;
    size_t P = (size_t)b * PP + (size_t)(yy + 1) * 98 + xx + 1;
    ushort8x rb[4], dh[4], dl[4], qh[4], ql[4];
    #pragma unroll
    for (int cc = 0; cc < 32; ++cc) {
        float r = tR[c0 + cc][p], q = tQ[c0 + cc][p];
        rb[cc >> 3][cc & 7] = f2bf(r);
        unsigned short h, l;
        split2(r - q, h, l); dh[cc >> 3][cc & 7] = h; dl[cc >> 3][cc & 7] = l;
        split2(q, h, l);     qh[cc >> 3][cc & 7] = h; ql[cc >> 3][cc & 7] = l;
    }
    #pragma unroll
    for (int i = 0; i < 4; ++i) {
        *(ushort8x*)&r1b[(size_t)pix * 128 + c0 + i * 8] = rb[i];
        *(ushort8x*)&diffb[P * 256 +       c0 + i * 8] = dh[i];
        *(ushort8x*)&diffb[P * 256 + 128 + c0 + i * 8] = dl[i];
        *(ushort8x*)&cat [P * 512 + 128 + c0 + i * 8] = qh[i];
        *(ushort8x*)&cat [P * 512 + 384 + c0 + i * 8] = ql[i];
    }
}

// ---------------------------------------------------------------------------
// Weight repack to bf16 hi/lo planes.
// p1/p2: [2][9][128][128]; pom: [2][9][256][128]; prq: [2][9][128][256]
// pdcn:  [2][128][1152], K-order = (g*9+t)*16 + (ci&15)  (gk-major)
__global__ __launch_bounds__(256) void prep_w(
    const float* __restrict__ w1, const float* __restrict__ w2,
    const float* __restrict__ wom, const float* __restrict__ bom,
    const float* __restrict__ wrq, const float* __restrict__ wdcn,
    unsigned short* __restrict__ p1, unsigned short* __restrict__ p2,
    unsigned short* __restrict__ pom, unsigned short* __restrict__ prq,
    unsigned short* __restrict__ pdcn, float* __restrict__ bomp)
{
    int idx = blockIdx.x * 256 + threadIdx.x;
    unsigned short h, l;
    if (idx < 147456) {                   // 9*128*128
        int t = idx / 16384, o = (idx >> 7) & 127, ci = idx & 127;
        int src = (o * 128 + ci) * 9 + t;
        split2(w1[src], h, l);  p1[idx] = h;  p1[idx + 147456] = l;
        split2(w2[src], h, l);  p2[idx] = h;  p2[idx + 147456] = l;
        int dd = o * 1152 + ((ci >> 4) * 9 + t) * 16 + (ci & 15);
        split2(wdcn[src], h, l); pdcn[dd] = h; pdcn[dd + 147456] = l;
    }
    if (idx < 294912) {
        { // om
            int t = idx / 32768, o = (idx >> 7) & 255, ci = idx & 127;
            float v = (o < OMC) ? wom[(o * 128 + ci) * 9 + t] : 0.f;
            split2(v, h, l); pom[idx] = h; pom[idx + 294912] = l;
        }
        { // rq
            int t = idx / 32768, o = (idx >> 8) & 127, ci = idx & 255;
            split2(wrq[(o * 256 + ci) * 9 + t], h, l);
            prq[idx] = h; prq[idx + 294912] = l;
        }
    }
    if (idx < 256) bomp[idx] = (idx < OMC) ? bom[idx] : 0.f;
}

// ---------------------------------------------------------------------------
// Shift-GEMM 3x3 conv on zero-padded NHWC hi/lo bf16, MFMA 16x16x32,
// 3-product compensation. Block = 48 px (half row) x 128 outs, 4 waves.
// 3-buffer LDS, stage 2 K-steps ahead, raw s_barrier with counted
// s_waitcnt vmcnt(L) (w0/w1: 6 loads/step -> vmcnt(6); w2/w3: 5 -> vmcnt(5)).
template<int CIN, int COUTP, int MODE, bool RELU>
__global__ __launch_bounds__(256, 2) void conv_mfma(
    const unsigned short* __restrict__ in,   // padded [2][98][98][2*CIN]
    const unsigned short* __restrict__ wpk,  // [2][9][COUTP][CIN]
    const float* __restrict__ bias,          // [COUTP]
    void* __restrict__ outv)
{
    constexpr int NKC = CIN / 32;
    constexpr int NSTEP = 9 * NKC;
    const size_t WPLANE = (size_t)9 * COUTP * CIN;

    __shared__ __align__(16) unsigned short s_buf[3][3072 + 8192];

    int tid = threadIdx.x;
    int wid = tid >> 6, lane = tid & 63;
    int r = lane & 15, q = lane >> 4;
    int bid = blockIdx.x;
    int swz = (bid & 7) * 48 + (bid >> 3);   // XCD-chunked (384 = 8*48)
    int rowid = swz >> 1, half = swz & 1;
    int b = rowid / 96, y = rowid % 96;
    int x0 = half * 48;
    int nbase = blockIdx.y * 128;

    auto stage = [&](int buf, int step) {
        int t = step / NKC, kc = step - t * NKC;
        int dy = t / 3 - 1, dx = t % 3 - 1;
        unsigned short* sb = &s_buf[buf][0];
        {
            int j = tid;
            int m = j >> 7, pl = (j >> 6) & 1, L = j & 63;
            int px = m * 16 + (L & 15), qd = L >> 4;
            const unsigned short* src = in +
                ((size_t)b * PP + (size_t)(y + 1 + dy) * 98 + (x0 + 1 + dx + px)) * (2 * CIN)
                + pl * CIN + kc * 32 + qd * 8;
            gld_lds16(src, sb + (size_t)(wid * 64) * 8);
        }
        if (tid < 128) {
            int j = 256 + tid;
            int m = j >> 7, pl = (j >> 6) & 1, L = j & 63;
            int px = m * 16 + (L & 15), qd = L >> 4;
            const unsigned short* src = in +
                ((size_t)b * PP + (size_t)(y + 1 + dy) * 98 + (x0 + 1 + dx + px)) * (2 * CIN)
                + pl * CIN + kc * 32 + qd * 8;
            gld_lds16(src, sb + (size_t)(256 + wid * 64) * 8);
        }
        const unsigned short* wbase = wpk + ((size_t)t * COUTP + nbase) * CIN + kc * 32;
        #pragma unroll
        for (int c = 0; c < 4; ++c) {
            int j = c * 256 + tid;
            int ni = (j >> 7) & 1, pl = (j >> 6) & 1, L = j & 63;
            int rr = L & 15, qq = L >> 4;
            const unsigned short* src = wbase + (size_t)pl * WPLANE
                + (size_t)(c * 32 + ni * 16 + rr) * CIN + qq * 8;
            gld_lds16(src, sb + 3072 + (size_t)(c * 256 + wid * 64) * 8);
        }
    };

    f32x4 acc[3][2] = {};

    auto compute = [&](int buf) {
        const unsigned short* sb = &s_buf[buf][0];
        short8x AH[3], AL[3], BH[2], BL[2];
        #pragma unroll
        for (int m = 0; m < 3; ++m) {
            AH[m] = *(const short8x*)(sb + m * 1024 + lane * 8);
            AL[m] = *(const short8x*)(sb + m * 1024 + 512 + lane * 8);
        }
        #pragma unroll
        for (int n = 0; n < 2; ++n) {
            BH[n] = *(const short8x*)(sb + 3072 + wid * 2048 + n * 1024 + lane * 8);
            BL[n] = *(const short8x*)(sb + 3072 + wid * 2048 + n * 1024 + 512 + lane * 8);
        }
        #pragma unroll
        for (int m = 0; m < 3; ++m) {
            #pragma unroll
            for (int n = 0; n < 2; ++n) {
                acc[m][n] = mfma16(AH[m], BH[n], acc[m][n]);
                acc[m][n] = mfma16(AL[m], BH[n], acc[m][n]);
                acc[m][n] = mfma16(AH[m], BL[n], acc[m][n]);
            }
        }
    };

    // Prologue: stage steps 0 and 1; wait for step 0 (leave step 1 in flight).
    stage(0, 0);
    stage(1, 1);
    if (tid < 128) asm volatile("s_waitcnt vmcnt(6)" ::: "memory");
    else           asm volatile("s_waitcnt vmcnt(5)" ::: "memory");
    __builtin_amdgcn_s_barrier();

    for (int k = 0; k < NSTEP; ++k) {
        const int nb = k + 2;
        if (nb < NSTEP) stage(nb % 3, nb);
        compute(k % 3);
        if (k + 1 < NSTEP) {
            if (nb < NSTEP) {
                if (tid < 128) asm volatile("s_waitcnt vmcnt(6)" ::: "memory");
                else           asm volatile("s_waitcnt vmcnt(5)" ::: "memory");
            } else {
                asm volatile("s_waitcnt vmcnt(0)" ::: "memory");
            }
            __builtin_amdgcn_s_barrier();
        }
    }

    #pragma unroll
    for (int m = 0; m < 3; ++m) {
        #pragma unroll
        for (int n = 0; n < 2; ++n) {
            int o = nbase + wid * 32 + n * 16 + r;
            float bv = bias[o];
            #pragma unroll
            for (int j = 0; j < 4; ++j) {
                int px = m * 16 + q * 4 + j;
                int xx = x0 + px;
                float v = acc[m][n][j] + bv;
                if (RELU) v = fmaxf(v, 0.f);
                if (MODE == 0) {
                    size_t P = (size_t)b * PP + (size_t)(y + 1) * 98 + xx + 1;
                    unsigned short h, l; split2(v, h, l);
                    ((unsigned short*)outv)[P * 2 * COUTP + o] = h;
                    ((unsigned short*)outv)[P * 2 * COUTP + COUTP + o] = l;
                } else if (MODE == 1) {
                    if (o < OMC)
                        ((unsigned short*)outv)[((size_t)b * HW + y * 96 + xx) * OMC + o] = f2bf(v);
                } else {
                    ((float*)outv)[((size_t)b * 128 + o) * HW + y * 96 + xx] = v;
                }
            }
        }
    }
}

// ---------------------------------------------------------------------------
// Deformable conv v2, T14 phase-overlap. 16 px/block, 256 thr, 3 blocks/CU.
// K split into halves (gk 0..35 / 36..71); s_v[2][16][584]. Flow:
//   om-stage -> gather half0 -> barrier
//   -> ISSUE half1 corner loads (2 items/thread, into regs)
//   -> Phase C half0 (72 MFMAs, hides the load latency)
//   -> blend+write half1 (+tail item, tid<64) -> barrier -> Phase C half1.
// Unit order 0..35 preserved -> bit-identical to the single-pass version.
__global__ __launch_bounds__(256, 3) void deform_mfma(
    const unsigned short* __restrict__ xb,   // [NPIX][128] bf16 NHWC (R1)
    const unsigned short* __restrict__ omf,  // [NPIX][216] bf16
    const unsigned short* __restrict__ wpk,  // [2][128][1152] gk-major
    const float* __restrict__ bias,          // [128]
    unsigned short* __restrict__ cat)        // [2][98][98][512]
{
    __shared__ __align__(16) unsigned short s_v[2][16][584];  // +8 pad per row
    __shared__ __align__(16) unsigned short s_om[16][216];

    int tid = threadIdx.x;
    int bid = blockIdx.x;
    int swzb = (bid & 7) * 144 + (bid >> 3);   // XCD-chunked (1152 = 8*144)
    int pix0 = swzb * 16;
    int b = pix0 / HW;

    // Stage om rows (16 px x 432B) into LDS, coalesced 16B chunks.
    for (int it = tid; it < 432; it += 256) {
        int p = it / 27, j = it - p * 27;
        *(ushort8x*)&s_om[p][j * 8] =
            *(const ushort8x*)&omf[(size_t)(pix0 + p) * OMC + j * 8];
    }
    __syncthreads();

    // prep: compute corners for item e of half hf, issue 8 corner loads.
    auto prep = [&](int hf, int e, ushort8x (&c0)[4], ushort8x (&c1)[4],
                    float (&cw)[4], int& pp, int& gl) {
        int p = e & 15, gkl = e >> 4;
        int gk = hf * 36 + gkl;
        int pix = pix0 + p;
        int rem = pix % HW;
        int hh = rem / 96, ww = rem % 96;
        int g = gk / 9, k = gk - g * 9;
        const unsigned short* op = &s_om[p][0];
        float dy = bf2f(op[g * 18 + 2 * k]);
        float dx = bf2f(op[g * 18 + 2 * k + 1]);
        float mr = bf2f(op[144 + g * 9 + k]);
        float m = 1.f / (1.f + __expf(-mr));
        float py = dy + (float)(k / 3) + (float)hh - 1.f;
        float px = dx + (float)(k % 3) + (float)ww - 1.f;
        float fy = floorf(py), fx = floorf(px);
        int y0 = (int)fy, x0 = (int)fx;
        float ly = py - fy, lx = px - fx;
        float wj[4] = {(1.f - ly) * (1.f - lx), (1.f - ly) * lx,
                       ly * (1.f - lx), ly * lx};
        #pragma unroll
        for (int j = 0; j < 4; ++j) {
            int yy = y0 + (j >> 1), xx = x0 + (j & 1);
            bool valid = ((unsigned)yy < 96u) && ((unsigned)xx < 96u);
            int yc = min(max(yy, 0), 95), xc = min(max(xx, 0), 95);
            const unsigned short* cp =
                xb + ((size_t)(b * HW + yc * 96 + xc)) * 128 + g * 16;
            c0[j] = *(const ushort8x*)cp;
            c1[j] = *(const ushort8x*)(cp + 8);
            cw[j] = valid ? wj[j] * m : 0.f;
        }
        pp = p; gl = gkl;
    };
    auto finish = [&](int hf, ushort8x (&c0)[4], ushort8x (&c1)[4],
                      float (&cw)[4], int pp, int gl) {
        ushort8x o0, o1;
        #pragma unroll
        for (int i = 0; i < 8; ++i) {
            float v0 = cw[0]*bf2f(c0[0][i]) + cw[1]*bf2f(c0[1][i])
                     + cw[2]*bf2f(c0[2][i]) + cw[3]*bf2f(c0[3][i]);
            float v1 = cw[0]*bf2f(c1[0][i]) + cw[1]*bf2f(c1[1][i])
                     + cw[2]*bf2f(c1[2][i]) + cw[3]*bf2f(c1[3][i]);
            o0[i] = f2bf(v0);
            o1[i] = f2bf(v1);
        }
        *(ushort8x*)&s_v[hf][pp][gl * 16    ] = o0;
        *(ushort8x*)&s_v[hf][pp][gl * 16 + 8] = o1;
    };

    // Gather half 0 (plain).
    for (int e = tid; e < 576; e += 256) {
        ushort8x c0[4], c1[4]; float cw[4]; int pp, gl;
        prep(0, e, c0, c1, cw, pp, gl);
        finish(0, c0, c1, cw, pp, gl);
    }
    __syncthreads();

    int wid = tid >> 6, lane = tid & 63;
    int r = lane & 15, q = lane >> 4;
    int n0 = wid * 32;
    f32x4 acc0 = {}, acc1 = {};
    const unsigned short* wb = wpk + (size_t)(n0 + r) * 1152 + q * 8;

    auto phaseC = [&](int hf) {
        __builtin_amdgcn_s_setprio(1);
        #pragma unroll
        for (int kpl = 0; kpl < 9; ++kpl) {
            const int k0 = hf * 18 + kpl * 2, k1 = k0 + 1;
            short8x a0 = *(const short8x*)&s_v[hf][r][kpl * 64 + q * 8];
            short8x a1 = *(const short8x*)&s_v[hf][r][kpl * 64 + 32 + q * 8];
            short8x w00 = *(const short8x*)(wb + k0 * 32);
            short8x w10 = *(const short8x*)(wb + (size_t)16 * 1152 + k0 * 32);
            short8x l00 = *(const short8x*)(wb + 147456 + k0 * 32);
            short8x l10 = *(const short8x*)(wb + 147456 + (size_t)16 * 1152 + k0 * 32);
            short8x w01 = *(const short8x*)(wb + k1 * 32);
            short8x w11 = *(const short8x*)(wb + (size_t)16 * 1152 + k1 * 32);
            short8x l01 = *(const short8x*)(wb + 147456 + k1 * 32);
            short8x l11 = *(const short8x*)(wb + 147456 + (size_t)16 * 1152 + k1 * 32);
            acc0 = mfma16(a0, w00, acc0);
            acc1 = mfma16(a0, w10, acc1);
            acc0 = mfma16(a0, l00, acc0);
            acc1 = mfma16(a0, l10, acc1);
            acc0 = mfma16(a1, w01, acc0);
            acc1 = mfma16(a1, w11, acc1);
            acc0 = mfma16(a1, l01, acc0);
            acc1 = mfma16(a1, l11, acc1);
        }
        __builtin_amdgcn_s_setprio(0);
    };

    // Issue half-1 gather loads (2 items) BEFORE Phase C half 0.
    ushort8x Ac0[4], Ac1[4]; float Acw[4]; int Ap, Agl;
    ushort8x Bc0[4], Bc1[4]; float Bcw[4]; int Bp, Bgl;
    prep(1, tid,       Ac0, Ac1, Acw, Ap, Agl);
    prep(1, tid + 256, Bc0, Bc1, Bcw, Bp, Bgl);
    asm volatile("" ::: "memory");   // pin the loads before Phase C

    phaseC(0);                       // hides half-1 gather latency

    finish(1, Ac0, Ac1, Acw, Ap, Agl);
    finish(1, Bc0, Bc1, Bcw, Bp, Bgl);
    if (tid < 64) {
        prep(1, tid + 512, Ac0, Ac1, Acw, Ap, Agl);
        finish(1, Ac0, Ac1, Acw, Ap, Agl);
    }
    __syncthreads();

    phaseC(1);

    #pragma unroll
    for (int ni = 0; ni < 2; ++ni) {
        f32x4 A = ni ? acc1 : acc0;
        int o = n0 + ni * 16 + r;
        float bv = bias[o];
        #pragma unroll
        for (int j = 0; j < 4; ++j) {
            int pixel = pix0 + q * 4 + j;
            int bb = pixel / HW, rm = pixel % HW;
            int yy = rm / 96, xx = rm % 96;
            size_t P = (size_t)bb * PP + (size_t)(yy + 1) * 98 + xx + 1;
            float v = fmaxf(A[j] + bv, 0.f);
            unsigned short h, l;
            split2(v, h, l);
            cat[P * 512 + o] = h;
            cat[P * 512 + 256 + o] = l;
        }
    }
}

// ---------------------------------------------------------------------------
extern "C" void kernel_launch(void* const* d_in, const int* in_sizes, int n_in,
                              void* d_out, int out_size, void* d_ws, size_t ws_size,
                              hipStream_t stream) {
    const float* R1    = (const float*)d_in[0];
    const float* Q0    = (const float*)d_in[1];
    const float* w1    = (const float*)d_in[2];
    const float* b1    = (const float*)d_in[3];
    const float* w2    = (const float*)d_in[4];
    const float* b2    = (const float*)d_in[5];
    const float* w_om  = (const float*)d_in[6];
    const float* b_om  = (const float*)d_in[7];
    const float* w_dcn = (const float*)d_in[8];
    const float* b_dcn = (const float*)d_in[9];
    const float* w_rq  = (const float*)d_in[10];
    const float* b_rq  = (const float*)d_in[11];
    float* outp = (float*)d_out;

    // Arena ~48 MiB (R8 layout). Padded activations [2][98][98][C].
    char* w = (char*)d_ws;
    unsigned short* r1b   = (unsigned short*)w; w += (size_t)NPIX * 128 * 2;      // 4.72 MB
    unsigned short* diffb = (unsigned short*)w; w += (size_t)2 * PP * 256 * 2;    // 9.83 MB (also t2)
    unsigned short* t1    = (unsigned short*)w; w += (size_t)2 * PP * 256 * 2;    // 9.83 MB (also omf)
    unsigned short* catb  = (unsigned short*)w; w += (size_t)2 * PP * 512 * 2;    // 19.67 MB
    unsigned short* p1    = (unsigned short*)w; w += 2 * 147456 * 2;
    unsigned short* p2    = (unsigned short*)w; w += 2 * 147456 * 2;
    unsigned short* pdcn  = (unsigned short*)w; w += 2 * 147456 * 2;
    unsigned short* pom   = (unsigned short*)w; w += 2 * 294912 * 2;
    unsigned short* prq   = (unsigned short*)w; w += 2 * 294912 * 2;
    float*          bomp  = (float*)w;          w += 256 * 4;
    unsigned short* t2    = diffb;   // diff dead after conv1
    unsigned short* omf   = t1;      // t1 dead after conv2; bf16 [NPIX][216]

    zero_borders<<<388, 256, 0, stream>>>(diffb, t1, catb);
    prep_acts<<<288, 256, 0, stream>>>(R1, Q0, r1b, diffb, catb);
    prep_w<<<1152, 256, 0, stream>>>(w1, w2, w_om, b_om, w_rq, w_dcn,
                                     p1, p2, pom, prq, pdcn, bomp);

    conv_mfma<128, 128, 0, true ><<<dim3(384, 1), 256, 0, stream>>>(diffb, p1, b1, t1);
    conv_mfma<128, 128, 0, true ><<<dim3(384, 1), 256, 0, stream>>>(t1,    p2, b2, t2);
    conv_mfma<128, 256, 1, false><<<dim3(384, 2), 256, 0, stream>>>(t2,   pom, bomp, omf);

    deform_mfma<<<1152, 256, 0, stream>>>(r1b, omf, pdcn, b_dcn, catb);

    conv_mfma<256, 128, 2, true ><<<dim3(384, 1), 256, 0, stream>>>(catb, prq, b_rq, outp);
}

// Round 23
// 387.353 us; speedup vs baseline: 1.0015x; 1.0015x over previous
//
#include <hip/hip_runtime.h>

#define HH 96
#define WW 96
#define HW 9216
#define NPIX 18432      // B*H*W, B=2
#define OMC 216
#define PP 9604         // 98*98 padded image

typedef __attribute__((ext_vector_type(8))) short short8x;       // MFMA bf16 frag
typedef __attribute__((ext_vector_type(8))) unsigned short ushort8x;
typedef __attribute__((ext_vector_type(4))) float f32x4;

__device__ __forceinline__ f32x4 mfma16(short8x a, short8x b, f32x4 c) {
    return __builtin_amdgcn_mfma_f32_16x16x32_bf16(a, b, c, 0, 0, 0);
}
__device__ __forceinline__ unsigned short f2bf(float f) {
    unsigned int u = __float_as_uint(f);
    u = (u + 0x7FFFu + ((u >> 16) & 1u)) >> 16;   // RNE (finite values)
    return (unsigned short)u;
}
__device__ __forceinline__ float bf2f(unsigned short b) {
    return __uint_as_float((unsigned int)b << 16);
}
__device__ __forceinline__ void split2(float v, unsigned short& h, unsigned short& l) {
    h = f2bf(v);
    l = f2bf(v - bf2f(h));
}
__device__ __forceinline__ void gld_lds16(const unsigned short* src, unsigned short* dst) {
    __builtin_amdgcn_global_load_lds(
        (const __attribute__((address_space(1))) unsigned int*)src,
        (__attribute__((address_space(3))) unsigned int*)dst, 16, 0, 0);
}

// ---------------------------------------------------------------------------
// Zero the 1-px border of the padded activation buffers. Fully parallel:
// one 16B store per thread (776 border px x 128 stores = 99328 items).
__global__ __launch_bounds__(256) void zero_borders(
    unsigned short* __restrict__ diffb,   // [2][98][98][256]
    unsigned short* __restrict__ t1,      // [2][98][98][256]
    unsigned short* __restrict__ catb)    // [2][98][98][512]
{
    int idx = blockIdx.x * 256 + threadIdx.x;
    if (idx >= 99328) return;
    int i = idx >> 7, sub = idx & 127;
    int b = i / 388, r = i % 388;
    int y, x;
    if      (r < 98)  { y = 0;           x = r; }
    else if (r < 196) { y = 97;          x = r - 98; }
    else if (r < 292) { y = r - 196 + 1; x = 0; }
    else              { y = r - 292 + 1; x = 97; }
    size_t P = (size_t)b * PP + (size_t)y * 98 + x;
    ushort8x z = {};
    if (sub < 32)      *(ushort8x*)&diffb[P * 256 + sub * 8] = z;
    else if (sub < 64) *(ushort8x*)&t1[P * 256 + (sub - 32) * 8] = z;
    else               *(ushort8x*)&catb[P * 512 + (sub - 64) * 8] = z;
}

// ---------------------------------------------------------------------------
// NCHW fp32 -> r1b (bf16 NHWC, gather src), diff=R1-Q0 (hi/lo bf16, padded),
// Q0 -> padded cat channels (hi 128..255, lo 384..511). 64 pixels per block.
__global__ __launch_bounds__(256) void prep_acts(
    const float* __restrict__ R1, const float* __restrict__ Q0,
    unsigned short* __restrict__ r1b,    // [NPIX][128] bf16
    unsigned short* __restrict__ diffb,  // [2][98][98][256] hi|lo
    unsigned short* __restrict__ cat)    // [2][98][98][512]
{
    __shared__ float tR[128][64];
    __shared__ float tQ[128][64];
    int tid = threadIdx.x;
    int p0  = blockIdx.x * 64;
    int b   = p0 / HW;
    int rem0 = p0 % HW;

    for (int e = tid; e < 2048; e += 256) {          // 128 ch x 16 float4
        int c = e >> 4, j = e & 15;
        size_t base = ((size_t)(b * 128 + c)) * HW + rem0;
        *(float4*)&tR[c][j * 4] = *(const float4*)(R1 + base + j * 4);
        *(float4*)&tQ[c][j * 4] = *(const float4*)(Q0 + base + j * 4);
    }
    __syncthreads();

    int p = tid & 63, half = tid >> 6;   // half 0..3
    int c0 = half * 32;
    int pix = p0 + p;
    int rm = pix % HW, yy = rm / 96, xx = rm % 96;
    size_t P = (size_t)b * PP + (size_t)(yy + 1) * 98 + xx + 1;
    ushort8x rb[4], dh[4], dl[4], qh[4], ql[4];
    #pragma unroll
    for (int cc = 0; cc < 32; ++cc) {
        float r = tR[c0 + cc][p], q = tQ[c0 + cc][p];
        rb[cc >> 3][cc & 7] = f2bf(r);
        unsigned short h, l;
        split2(r - q, h, l); dh[cc >> 3][cc & 7] = h; dl[cc >> 3][cc & 7] = l;
        split2(q, h, l);     qh[cc >> 3][cc & 7] = h; ql[cc >> 3][cc & 7] = l;
    }
    #pragma unroll
    for (int i = 0; i < 4; ++i) {
        *(ushort8x*)&r1b[(size_t)pix * 128 + c0 + i * 8] = rb[i];
        *(ushort8x*)&diffb[P * 256 +       c0 + i * 8] = dh[i];
        *(ushort8x*)&diffb[P * 256 + 128 + c0 + i * 8] = dl[i];
        *(ushort8x*)&cat [P * 512 + 128 + c0 + i * 8] = qh[i];
        *(ushort8x*)&cat [P * 512 + 384 + c0 + i * 8] = ql[i];
    }
}

// ---------------------------------------------------------------------------
// Weight repack to bf16 hi/lo planes.
// p1/p2: [2][9][128][128]; pom: [2][9][256][128]; prq: [2][9][128][256]
// pdcn:  [2][128][1152], K-order = (g*9+t)*16 + (ci&15)  (gk-major)
__global__ __launch_bounds__(256) void prep_w(
    const float* __restrict__ w1, const float* __restrict__ w2,
    const float* __restrict__ wom, const float* __restrict__ bom,
    const float* __restrict__ wrq, const float* __restrict__ wdcn,
    unsigned short* __restrict__ p1, unsigned short* __restrict__ p2,
    unsigned short* __restrict__ pom, unsigned short* __restrict__ prq,
    unsigned short* __restrict__ pdcn, float* __restrict__ bomp)
{
    int idx = blockIdx.x * 256 + threadIdx.x;
    unsigned short h, l;
    if (idx < 147456) {                   // 9*128*128
        int t = idx / 16384, o = (idx >> 7) & 127, ci = idx & 127;
        int src = (o * 128 + ci) * 9 + t;
        split2(w1[src], h, l);  p1[idx] = h;  p1[idx + 147456] = l;
        split2(w2[src], h, l);  p2[idx] = h;  p2[idx + 147456] = l;
        int dd = o * 1152 + ((ci >> 4) * 9 + t) * 16 + (ci & 15);
        split2(wdcn[src], h, l); pdcn[dd] = h; pdcn[dd + 147456] = l;
    }
    if (idx < 294912) {
        { // om
            int t = idx / 32768, o = (idx >> 7) & 255, ci = idx & 127;
            float v = (o < OMC) ? wom[(o * 128 + ci) * 9 + t] : 0.f;
            split2(v, h, l); pom[idx] = h; pom[idx + 294912] = l;
        }
        { // rq
            int t = idx / 32768, o = (idx >> 8) & 127, ci = idx & 255;
            split2(wrq[(o * 256 + ci) * 9 + t], h, l);
            prq[idx] = h; prq[idx + 294912] = l;
        }
    }
    if (idx < 256) bomp[idx] = (idx < OMC) ? bom[idx] : 0.f;
}

// ---------------------------------------------------------------------------
// Shift-GEMM 3x3 conv on zero-padded NHWC hi/lo bf16, MFMA 16x16x32,
// 3-product compensation. Block = 48 px (half row) x 128 outs, 4 waves.
// 3-buffer LDS, stage 2 K-steps ahead, raw s_barrier with counted
// s_waitcnt vmcnt(L) (w0/w1: 6 loads/step -> vmcnt(6); w2/w3: 5 -> vmcnt(5)).
template<int CIN, int COUTP, int MODE, bool RELU>
__global__ __launch_bounds__(256, 2) void conv_mfma(
    const unsigned short* __restrict__ in,   // padded [2][98][98][2*CIN]
    const unsigned short* __restrict__ wpk,  // [2][9][COUTP][CIN]
    const float* __restrict__ bias,          // [COUTP]
    void* __restrict__ outv)
{
    constexpr int NKC = CIN / 32;
    constexpr int NSTEP = 9 * NKC;
    const size_t WPLANE = (size_t)9 * COUTP * CIN;

    __shared__ __align__(16) unsigned short s_buf[3][3072 + 8192];

    int tid = threadIdx.x;
    int wid = tid >> 6, lane = tid & 63;
    int r = lane & 15, q = lane >> 4;
    int bid = blockIdx.x;
    int swz = (bid & 7) * 48 + (bid >> 3);   // XCD-chunked (384 = 8*48)
    int rowid = swz >> 1, half = swz & 1;
    int b = rowid / 96, y = rowid % 96;
    int x0 = half * 48;
    int nbase = blockIdx.y * 128;

    auto stage = [&](int buf, int step) {
        int t = step / NKC, kc = step - t * NKC;
        int dy = t / 3 - 1, dx = t % 3 - 1;
        unsigned short* sb = &s_buf[buf][0];
        {
            int j = tid;
            int m = j >> 7, pl = (j >> 6) & 1, L = j & 63;
            int px = m * 16 + (L & 15), qd = L >> 4;
            const unsigned short* src = in +
                ((size_t)b * PP + (size_t)(y + 1 + dy) * 98 + (x0 + 1 + dx + px)) * (2 * CIN)
                + pl * CIN + kc * 32 + qd * 8;
            gld_lds16(src, sb + (size_t)(wid * 64) * 8);
        }
        if (tid < 128) {
            int j = 256 + tid;
            int m = j >> 7, pl = (j >> 6) & 1, L = j & 63;
            int px = m * 16 + (L & 15), qd = L >> 4;
            const unsigned short* src = in +
                ((size_t)b * PP + (size_t)(y + 1 + dy) * 98 + (x0 + 1 + dx + px)) * (2 * CIN)
                + pl * CIN + kc * 32 + qd * 8;
            gld_lds16(src, sb + (size_t)(256 + wid * 64) * 8);
        }
        const unsigned short* wbase = wpk + ((size_t)t * COUTP + nbase) * CIN + kc * 32;
        #pragma unroll
        for (int c = 0; c < 4; ++c) {
            int j = c * 256 + tid;
            int ni = (j >> 7) & 1, pl = (j >> 6) & 1, L = j & 63;
            int rr = L & 15, qq = L >> 4;
            const unsigned short* src = wbase + (size_t)pl * WPLANE
                + (size_t)(c * 32 + ni * 16 + rr) * CIN + qq * 8;
            gld_lds16(src, sb + 3072 + (size_t)(c * 256 + wid * 64) * 8);
        }
    };

    f32x4 acc[3][2] = {};

    auto compute = [&](int buf) {
        const unsigned short* sb = &s_buf[buf][0];
        short8x AH[3], AL[3], BH[2], BL[2];
        #pragma unroll
        for (int m = 0; m < 3; ++m) {
            AH[m] = *(const short8x*)(sb + m * 1024 + lane * 8);
            AL[m] = *(const short8x*)(sb + m * 1024 + 512 + lane * 8);
        }
        #pragma unroll
        for (int n = 0; n < 2; ++n) {
            BH[n] = *(const short8x*)(sb + 3072 + wid * 2048 + n * 1024 + lane * 8);
            BL[n] = *(const short8x*)(sb + 3072 + wid * 2048 + n * 1024 + 512 + lane * 8);
        }
        #pragma unroll
        for (int m = 0; m < 3; ++m) {
            #pragma unroll
            for (int n = 0; n < 2; ++n) {
                acc[m][n] = mfma16(AH[m], BH[n], acc[m][n]);
                acc[m][n] = mfma16(AL[m], BH[n], acc[m][n]);
                acc[m][n] = mfma16(AH[m], BL[n], acc[m][n]);
            }
        }
    };

    // Prologue: stage steps 0 and 1; wait for step 0 (leave step 1 in flight).
    stage(0, 0);
    stage(1, 1);
    if (tid < 128) asm volatile("s_waitcnt vmcnt(6)" ::: "memory");
    else           asm volatile("s_waitcnt vmcnt(5)" ::: "memory");
    __builtin_amdgcn_s_barrier();

    for (int k = 0; k < NSTEP; ++k) {
        const int nb = k + 2;
        if (nb < NSTEP) stage(nb % 3, nb);
        compute(k % 3);
        if (k + 1 < NSTEP) {
            if (nb < NSTEP) {
                if (tid < 128) asm volatile("s_waitcnt vmcnt(6)" ::: "memory");
                else           asm volatile("s_waitcnt vmcnt(5)" ::: "memory");
            } else {
                asm volatile("s_waitcnt vmcnt(0)" ::: "memory");
            }
            __builtin_amdgcn_s_barrier();
        }
    }

    #pragma unroll
    for (int m = 0; m < 3; ++m) {
        #pragma unroll
        for (int n = 0; n < 2; ++n) {
            int o = nbase + wid * 32 + n * 16 + r;
            float bv = bias[o];
            #pragma unroll
            for (int j = 0; j < 4; ++j) {
                int px = m * 16 + q * 4 + j;
                int xx = x0 + px;
                float v = acc[m][n][j] + bv;
                if (RELU) v = fmaxf(v, 0.f);
                if (MODE == 0) {
                    size_t P = (size_t)b * PP + (size_t)(y + 1) * 98 + xx + 1;
                    unsigned short h, l; split2(v, h, l);
                    ((unsigned short*)outv)[P * 2 * COUTP + o] = h;
                    ((unsigned short*)outv)[P * 2 * COUTP + COUTP + o] = l;
                } else if (MODE == 1) {
                    if (o < OMC)
                        ((unsigned short*)outv)[((size_t)b * HW + y * 96 + xx) * OMC + o] = f2bf(v);
                } else {
                    ((float*)outv)[((size_t)b * 128 + o) * HW + y * 96 + xx] = v;
                }
            }
        }
    }
}

// ---------------------------------------------------------------------------
// Deformable conv v2, T14 phase-overlap. 16 px/block, 256 thr, 3 blocks/CU.
// K split into halves (gk 0..35 / 36..71); s_v[2][16][584]. Flow:
//   om-stage -> gather half0 -> barrier
//   -> ISSUE half1 corner loads (2 items/thread, into regs)
//   -> Phase C half0 (72 MFMAs, hides the load latency)
//   -> blend+write half1 (+tail item, tid<64) -> barrier -> Phase C half1.
// Unit order 0..35 preserved -> bit-identical to the single-pass version.
__global__ __launch_bounds__(256, 3) void deform_mfma(
    const unsigned short* __restrict__ xb,   // [NPIX][128] bf16 NHWC (R1)
    const unsigned short* __restrict__ omf,  // [NPIX][216] bf16
    const unsigned short* __restrict__ wpk,  // [2][128][1152] gk-major
    const float* __restrict__ bias,          // [128]
    unsigned short* __restrict__ cat)        // [2][98][98][512]
{
    __shared__ __align__(16) unsigned short s_v[2][16][584];  // +8 pad per row
    __shared__ __align__(16) unsigned short s_om[16][216];

    int tid = threadIdx.x;
    int bid = blockIdx.x;
    int swzb = (bid & 7) * 144 + (bid >> 3);   // XCD-chunked (1152 = 8*144)
    int pix0 = swzb * 16;
    int b = pix0 / HW;

    // Stage om rows (16 px x 432B) into LDS, coalesced 16B chunks.
    for (int it = tid; it < 432; it += 256) {
        int p = it / 27, j = it - p * 27;
        *(ushort8x*)&s_om[p][j * 8] =
            *(const ushort8x*)&omf[(size_t)(pix0 + p) * OMC + j * 8];
    }
    __syncthreads();

    // prep: compute corners for item e of half hf, issue 8 corner loads.
    auto prep = [&](int hf, int e, ushort8x (&c0)[4], ushort8x (&c1)[4],
                    float (&cw)[4], int& pp, int& gl) {
        int p = e & 15, gkl = e >> 4;
        int gk = hf * 36 + gkl;
        int pix = pix0 + p;
        int rem = pix % HW;
        int hh = rem / 96, ww = rem % 96;
        int g = gk / 9, k = gk - g * 9;
        const unsigned short* op = &s_om[p][0];
        float dy = bf2f(op[g * 18 + 2 * k]);
        float dx = bf2f(op[g * 18 + 2 * k + 1]);
        float mr = bf2f(op[144 + g * 9 + k]);
        float m = 1.f / (1.f + __expf(-mr));
        float py = dy + (float)(k / 3) + (float)hh - 1.f;
        float px = dx + (float)(k % 3) + (float)ww - 1.f;
        float fy = floorf(py), fx = floorf(px);
        int y0 = (int)fy, x0 = (int)fx;
        float ly = py - fy, lx = px - fx;
        float wj[4] = {(1.f - ly) * (1.f - lx), (1.f - ly) * lx,
                       ly * (1.f - lx), ly * lx};
        #pragma unroll
        for (int j = 0; j < 4; ++j) {
            int yy = y0 + (j >> 1), xx = x0 + (j & 1);
            bool valid = ((unsigned)yy < 96u) && ((unsigned)xx < 96u);
            int yc = min(max(yy, 0), 95), xc = min(max(xx, 0), 95);
            const unsigned short* cp =
                xb + ((size_t)(b * HW + yc * 96 + xc)) * 128 + g * 16;
            c0[j] = *(const ushort8x*)cp;
            c1[j] = *(const ushort8x*)(cp + 8);
            cw[j] = valid ? wj[j] * m : 0.f;
        }
        pp = p; gl = gkl;
    };
    auto finish = [&](int hf, ushort8x (&c0)[4], ushort8x (&c1)[4],
                      float (&cw)[4], int pp, int gl) {
        ushort8x o0, o1;
        #pragma unroll
        for (int i = 0; i < 8; ++i) {
            float v0 = cw[0]*bf2f(c0[0][i]) + cw[1]*bf2f(c0[1][i])
                     + cw[2]*bf2f(c0[2][i]) + cw[3]*bf2f(c0[3][i]);
            float v1 = cw[0]*bf2f(c1[0][i]) + cw[1]*bf2f(c1[1][i])
                     + cw[2]*bf2f(c1[2][i]) + cw[3]*bf2f(c1[3][i]);
            o0[i] = f2bf(v0);
            o1[i] = f2bf(v1);
        }
        *(ushort8x*)&s_v[hf][pp][gl * 16    ] = o0;
        *(ushort8x*)&s_v[hf][pp][gl * 16 + 8] = o1;
    };

    // Gather half 0 (plain).
    for (int e = tid; e < 576; e += 256) {
        ushort8x c0[4], c1[4]; float cw[4]; int pp, gl;
        prep(0, e, c0, c1, cw, pp, gl);
        finish(0, c0, c1, cw, pp, gl);
    }
    __syncthreads();

    int wid = tid >> 6, lane = tid & 63;
    int r = lane & 15, q = lane >> 4;
    int n0 = wid * 32;
    f32x4 acc0 = {}, acc1 = {};
    const unsigned short* wb = wpk + (size_t)(n0 + r) * 1152 + q * 8;

    auto phaseC = [&](int hf) {
        __builtin_amdgcn_s_setprio(1);
        #pragma unroll
        for (int kpl = 0; kpl < 9; ++kpl) {
            const int k0 = hf * 18 + kpl * 2, k1 = k0 + 1;
            short8x a0 = *(const short8x*)&s_v[hf][r][kpl * 64 + q * 8];
            short8x a1 = *(const short8x*)&s_v[hf][r][kpl * 64 + 32 + q * 8];
            short8x w00 = *(const short8x*)(wb + k0 * 32);
            short8x w10 = *(const short8x*)(wb + (size_t)16 * 1152 + k0 * 32);
            short8x l00 = *(const short8x*)(wb + 147456 + k0 * 32);
            short8x l10 = *(const short8x*)(wb + 147456 + (size_t)16 * 1152 + k0 * 32);
            short8x w01 = *(const short8x*)(wb + k1 * 32);
            short8x w11 = *(const short8x*)(wb + (size_t)16 * 1152 + k1 * 32);
            short8x l01 = *(const short8x*)(wb + 147456 + k1 * 32);
            short8x l11 = *(const short8x*)(wb + 147456 + (size_t)16 * 1152 + k1 * 32);
            acc0 = mfma16(a0, w00, acc0);
            acc1 = mfma16(a0, w10, acc1);
            acc0 = mfma16(a0, l00, acc0);
            acc1 = mfma16(a0, l10, acc1);
            acc0 = mfma16(a1, w01, acc0);
            acc1 = mfma16(a1, w11, acc1);
            acc0 = mfma16(a1, l01, acc0);
            acc1 = mfma16(a1, l11, acc1);
        }
        __builtin_amdgcn_s_setprio(0);
    };

    // Issue half-1 gather loads (2 items) BEFORE Phase C half 0.
    ushort8x Ac0[4], Ac1[4]; float Acw[4]; int Ap, Agl;
    ushort8x Bc0[4], Bc1[4]; float Bcw[4]; int Bp, Bgl;
    prep(1, tid,       Ac0, Ac1, Acw, Ap, Agl);
    prep(1, tid + 256, Bc0, Bc1, Bcw, Bp, Bgl);
    asm volatile("" ::: "memory");   // pin the loads before Phase C

    phaseC(0);                       // hides half-1 gather latency

    finish(1, Ac0, Ac1, Acw, Ap, Agl);
    finish(1, Bc0, Bc1, Bcw, Bp, Bgl);
    if (tid < 64) {
        prep(1, tid + 512, Ac0, Ac1, Acw, Ap, Agl);
        finish(1, Ac0, Ac1, Acw, Ap, Agl);
    }
    __syncthreads();

    phaseC(1);

    #pragma unroll
    for (int ni = 0; ni < 2; ++ni) {
        f32x4 A = ni ? acc1 : acc0;
        int o = n0 + ni * 16 + r;
        float bv = bias[o];
        #pragma unroll
        for (int j = 0; j < 4; ++j) {
            int pixel = pix0 + q * 4 + j;
            int bb = pixel / HW, rm = pixel % HW;
            int yy = rm / 96, xx = rm % 96;
            size_t P = (size_t)bb * PP + (size_t)(yy + 1) * 98 + xx + 1;
            float v = fmaxf(A[j] + bv, 0.f);
            unsigned short h, l;
            split2(v, h, l);
            cat[P * 512 + o] = h;
            cat[P * 512 + 256 + o] = l;
        }
    }
}

// ---------------------------------------------------------------------------
extern "C" void kernel_launch(void* const* d_in, const int* in_sizes, int n_in,
                              void* d_out, int out_size, void* d_ws, size_t ws_size,
                              hipStream_t stream) {
    const float* R1    = (const float*)d_in[0];
    const float* Q0    = (const float*)d_in[1];
    const float* w1    = (const float*)d_in[2];
    const float* b1    = (const float*)d_in[3];
    const float* w2    = (const float*)d_in[4];
    const float* b2    = (const float*)d_in[5];
    const float* w_om  = (const float*)d_in[6];
    const float* b_om  = (const float*)d_in[7];
    const float* w_dcn = (const float*)d_in[8];
    const float* b_dcn = (const float*)d_in[9];
    const float* w_rq  = (const float*)d_in[10];
    const float* b_rq  = (const float*)d_in[11];
    float* outp = (float*)d_out;

    // Arena ~48 MiB (R8 layout). Padded activations [2][98][98][C].
    char* w = (char*)d_ws;
    unsigned short* r1b   = (unsigned short*)w; w += (size_t)NPIX * 128 * 2;      // 4.72 MB
    unsigned short* diffb = (unsigned short*)w; w += (size_t)2 * PP * 256 * 2;    // 9.83 MB (also t2)
    unsigned short* t1    = (unsigned short*)w; w += (size_t)2 * PP * 256 * 2;    // 9.83 MB (also omf)
    unsigned short* catb  = (unsigned short*)w; w += (size_t)2 * PP * 512 * 2;    // 19.67 MB
    unsigned short* p1    = (unsigned short*)w; w += 2 * 147456 * 2;
    unsigned short* p2    = (unsigned short*)w; w += 2 * 147456 * 2;
    unsigned short* pdcn  = (unsigned short*)w; w += 2 * 147456 * 2;
    unsigned short* pom   = (unsigned short*)w; w += 2 * 294912 * 2;
    unsigned short* prq   = (unsigned short*)w; w += 2 * 294912 * 2;
    float*          bomp  = (float*)w;          w += 256 * 4;
    unsigned short* t2    = diffb;   // diff dead after conv1
    unsigned short* omf   = t1;      // t1 dead after conv2; bf16 [NPIX][216]

    zero_borders<<<388, 256, 0, stream>>>(diffb, t1, catb);
    prep_acts<<<288, 256, 0, stream>>>(R1, Q0, r1b, diffb, catb);
    prep_w<<<1152, 256, 0, stream>>>(w1, w2, w_om, b_om, w_rq, w_dcn,
                                     p1, p2, pom, prq, pdcn, bomp);

    conv_mfma<128, 128, 0, true ><<<dim3(384, 1), 256, 0, stream>>>(diffb, p1, b1, t1);
    conv_mfma<128, 128, 0, true ><<<dim3(384, 1), 256, 0, stream>>>(t1,    p2, b2, t2);
    conv_mfma<128, 256, 1, false><<<dim3(384, 2), 256, 0, stream>>>(t2,   pom, bomp, omf);

    deform_mfma<<<1152, 256, 0, stream>>>(r1b, omf, pdcn, b_dcn, catb);

    conv_mfma<256, 128, 2, true ><<<dim3(384, 1), 256, 0, stream>>>(catb, prq, b_rq, outp);
}

// Round 24
// 360.987 us; speedup vs baseline: 1.0747x; 1.0730x over previous
//
#include <hip/hip_runtime.h>

#define HH 96
#define WW 96
#define HW 9216
#define NPIX 18432      // B*H*W, B=2
#define OMC 216
#define PP 9604         // 98*98 padded image

typedef __attribute__((ext_vector_type(8))) short short8x;       // MFMA bf16 frag
typedef __attribute__((ext_vector_type(8))) unsigned short ushort8x;
typedef __attribute__((ext_vector_type(4))) float f32x4;

__device__ __forceinline__ f32x4 mfma16(short8x a, short8x b, f32x4 c) {
    return __builtin_amdgcn_mfma_f32_16x16x32_bf16(a, b, c, 0, 0, 0);
}
__device__ __forceinline__ unsigned short f2bf(float f) {
    unsigned int u = __float_as_uint(f);
    u = (u + 0x7FFFu + ((u >> 16) & 1u)) >> 16;   // RNE (finite values)
    return (unsigned short)u;
}
__device__ __forceinline__ float bf2f(unsigned short b) {
    return __uint_as_float((unsigned int)b << 16);
}
__device__ __forceinline__ void split2(float v, unsigned short& h, unsigned short& l) {
    h = f2bf(v);
    l = f2bf(v - bf2f(h));
}
__device__ __forceinline__ void gld_lds16(const unsigned short* src, unsigned short* dst) {
    __builtin_amdgcn_global_load_lds(
        (const __attribute__((address_space(1))) unsigned int*)src,
        (__attribute__((address_space(3))) unsigned int*)dst, 16, 0, 0);
}

// ---------------------------------------------------------------------------
// Zero the 1-px border of the padded activation buffers. Fully parallel:
// one 16B store per thread (776 border px x 128 stores = 99328 items).
__global__ __launch_bounds__(256) void zero_borders(
    unsigned short* __restrict__ diffb,   // [2][98][98][256]
    unsigned short* __restrict__ t1,      // [2][98][98][256]
    unsigned short* __restrict__ catb)    // [2][98][98][512]
{
    int idx = blockIdx.x * 256 + threadIdx.x;
    if (idx >= 99328) return;
    int i = idx >> 7, sub = idx & 127;
    int b = i / 388, r = i % 388;
    int y, x;
    if      (r < 98)  { y = 0;           x = r; }
    else if (r < 196) { y = 97;          x = r - 98; }
    else if (r < 292) { y = r - 196 + 1; x = 0; }
    else              { y = r - 292 + 1; x = 97; }
    size_t P = (size_t)b * PP + (size_t)y * 98 + x;
    ushort8x z = {};
    if (sub < 32)      *(ushort8x*)&diffb[P * 256 + sub * 8] = z;
    else if (sub < 64) *(ushort8x*)&t1[P * 256 + (sub - 32) * 8] = z;
    else               *(ushort8x*)&catb[P * 512 + (sub - 64) * 8] = z;
}

// ---------------------------------------------------------------------------
// NCHW fp32 -> r1b (bf16 NHWC, gather src), diff=R1-Q0 (hi/lo bf16, padded),
// Q0 -> padded cat channels (hi 128..255, lo 384..511). 64 pixels per block.
__global__ __launch_bounds__(256) void prep_acts(
    const float* __restrict__ R1, const float* __restrict__ Q0,
    unsigned short* __restrict__ r1b,    // [NPIX][128] bf16
    unsigned short* __restrict__ diffb,  // [2][98][98][256] hi|lo
    unsigned short* __restrict__ cat)    // [2][98][98][512]
{
    __shared__ float tR[128][64];
    __shared__ float tQ[128][64];
    int tid = threadIdx.x;
    int p0  = blockIdx.x * 64;
    int b   = p0 / HW;
    int rem0 = p0 % HW;

    for (int e = tid; e < 2048; e += 256) {          // 128 ch x 16 float4
        int c = e >> 4, j = e & 15;
        size_t base = ((size_t)(b * 128 + c)) * HW + rem0;
        *(float4*)&tR[c][j * 4] = *(const float4*)(R1 + base + j * 4);
        *(float4*)&tQ[c][j * 4] = *(const float4*)(Q0 + base + j * 4);
    }
    __syncthreads();

    int p = tid & 63, half = tid >> 6;   // half 0..3
    int c0 = half * 32;
    int pix = p0 + p;
    int rm = pix % HW, yy = rm / 96, xx = rm % 96;
    size_t P = (size_t)b * PP + (size_t)(yy + 1) * 98 + xx + 1;
    ushort8x rb[4], dh[4], dl[4], qh[4], ql[4];
    #pragma unroll
    for (int cc = 0; cc < 32; ++cc) {
        float r = tR[c0 + cc][p], q = tQ[c0 + cc][p];
        rb[cc >> 3][cc & 7] = f2bf(r);
        unsigned short h, l;
        split2(r - q, h, l); dh[cc >> 3][cc & 7] = h; dl[cc >> 3][cc & 7] = l;
        split2(q, h, l);     qh[cc >> 3][cc & 7] = h; ql[cc >> 3][cc & 7] = l;
    }
    #pragma unroll
    for (int i = 0; i < 4; ++i) {
        *(ushort8x*)&r1b[(size_t)pix * 128 + c0 + i * 8] = rb[i];
        *(ushort8x*)&diffb[P * 256 +       c0 + i * 8] = dh[i];
        *(ushort8x*)&diffb[P * 256 + 128 + c0 + i * 8] = dl[i];
        *(ushort8x*)&cat [P * 512 + 128 + c0 + i * 8] = qh[i];
        *(ushort8x*)&cat [P * 512 + 384 + c0 + i * 8] = ql[i];
    }
}

// ---------------------------------------------------------------------------
// Weight repack to bf16 hi/lo planes.
// p1/p2: [2][9][128][128]; pom: [2][9][256][128]; prq: [2][9][128][256]
// pdcn:  [2][128][1152], K-order = (g*9+t)*16 + (ci&15)  (gk-major)
__global__ __launch_bounds__(256) void prep_w(
    const float* __restrict__ w1, const float* __restrict__ w2,
    const float* __restrict__ wom, const float* __restrict__ bom,
    const float* __restrict__ wrq, const float* __restrict__ wdcn,
    unsigned short* __restrict__ p1, unsigned short* __restrict__ p2,
    unsigned short* __restrict__ pom, unsigned short* __restrict__ prq,
    unsigned short* __restrict__ pdcn, float* __restrict__ bomp)
{
    int idx = blockIdx.x * 256 + threadIdx.x;
    unsigned short h, l;
    if (idx < 147456) {                   // 9*128*128
        int t = idx / 16384, o = (idx >> 7) & 127, ci = idx & 127;
        int src = (o * 128 + ci) * 9 + t;
        split2(w1[src], h, l);  p1[idx] = h;  p1[idx + 147456] = l;
        split2(w2[src], h, l);  p2[idx] = h;  p2[idx + 147456] = l;
        int dd = o * 1152 + ((ci >> 4) * 9 + t) * 16 + (ci & 15);
        split2(wdcn[src], h, l); pdcn[dd] = h; pdcn[dd + 147456] = l;
    }
    if (idx < 294912) {
        { // om
            int t = idx / 32768, o = (idx >> 7) & 255, ci = idx & 127;
            float v = (o < OMC) ? wom[(o * 128 + ci) * 9 + t] : 0.f;
            split2(v, h, l); pom[idx] = h; pom[idx + 294912] = l;
        }
        { // rq
            int t = idx / 32768, o = (idx >> 8) & 127, ci = idx & 255;
            split2(wrq[(o * 256 + ci) * 9 + t], h, l);
            prq[idx] = h; prq[idx + 294912] = l;
        }
    }
    if (idx < 256) bomp[idx] = (idx < OMC) ? bom[idx] : 0.f;
}

// ---------------------------------------------------------------------------
// Shift-GEMM 3x3 conv on zero-padded NHWC hi/lo bf16, MFMA 16x16x32,
// 3-product compensation. Block = 48 px (half row) x 128 outs, 4 waves.
// 3-buffer LDS, stage 2 K-steps ahead, raw s_barrier with counted
// s_waitcnt vmcnt(L) (w0/w1: 6 loads/step -> vmcnt(6); w2/w3: 5 -> vmcnt(5)).
template<int CIN, int COUTP, int MODE, bool RELU>
__global__ __launch_bounds__(256, 2) void conv_mfma(
    const unsigned short* __restrict__ in,   // padded [2][98][98][2*CIN]
    const unsigned short* __restrict__ wpk,  // [2][9][COUTP][CIN]
    const float* __restrict__ bias,          // [COUTP]
    void* __restrict__ outv)
{
    constexpr int NKC = CIN / 32;
    constexpr int NSTEP = 9 * NKC;
    const size_t WPLANE = (size_t)9 * COUTP * CIN;

    __shared__ __align__(16) unsigned short s_buf[3][3072 + 8192];

    int tid = threadIdx.x;
    int wid = tid >> 6, lane = tid & 63;
    int r = lane & 15, q = lane >> 4;
    int bid = blockIdx.x;
    int swz = (bid & 7) * 48 + (bid >> 3);   // XCD-chunked (384 = 8*48)
    int rowid = swz >> 1, half = swz & 1;
    int b = rowid / 96, y = rowid % 96;
    int x0 = half * 48;
    int nbase = blockIdx.y * 128;

    auto stage = [&](int buf, int step) {
        int t = step / NKC, kc = step - t * NKC;
        int dy = t / 3 - 1, dx = t % 3 - 1;
        unsigned short* sb = &s_buf[buf][0];
        {
            int j = tid;
            int m = j >> 7, pl = (j >> 6) & 1, L = j & 63;
            int px = m * 16 + (L & 15), qd = L >> 4;
            const unsigned short* src = in +
                ((size_t)b * PP + (size_t)(y + 1 + dy) * 98 + (x0 + 1 + dx + px)) * (2 * CIN)
                + pl * CIN + kc * 32 + qd * 8;
            gld_lds16(src, sb + (size_t)(wid * 64) * 8);
        }
        if (tid < 128) {
            int j = 256 + tid;
            int m = j >> 7, pl = (j >> 6) & 1, L = j & 63;
            int px = m * 16 + (L & 15), qd = L >> 4;
            const unsigned short* src = in +
                ((size_t)b * PP + (size_t)(y + 1 + dy) * 98 + (x0 + 1 + dx + px)) * (2 * CIN)
                + pl * CIN + kc * 32 + qd * 8;
            gld_lds16(src, sb + (size_t)(256 + wid * 64) * 8);
        }
        const unsigned short* wbase = wpk + ((size_t)t * COUTP + nbase) * CIN + kc * 32;
        #pragma unroll
        for (int c = 0; c < 4; ++c) {
            int j = c * 256 + tid;
            int ni = (j >> 7) & 1, pl = (j >> 6) & 1, L = j & 63;
            int rr = L & 15, qq = L >> 4;
            const unsigned short* src = wbase + (size_t)pl * WPLANE
                + (size_t)(c * 32 + ni * 16 + rr) * CIN + qq * 8;
            gld_lds16(src, sb + 3072 + (size_t)(c * 256 + wid * 64) * 8);
        }
    };

    f32x4 acc[3][2] = {};

    auto compute = [&](int buf) {
        const unsigned short* sb = &s_buf[buf][0];
        short8x AH[3], AL[3], BH[2], BL[2];
        #pragma unroll
        for (int m = 0; m < 3; ++m) {
            AH[m] = *(const short8x*)(sb + m * 1024 + lane * 8);
            AL[m] = *(const short8x*)(sb + m * 1024 + 512 + lane * 8);
        }
        #pragma unroll
        for (int n = 0; n < 2; ++n) {
            BH[n] = *(const short8x*)(sb + 3072 + wid * 2048 + n * 1024 + lane * 8);
            BL[n] = *(const short8x*)(sb + 3072 + wid * 2048 + n * 1024 + 512 + lane * 8);
        }
        #pragma unroll
        for (int m = 0; m < 3; ++m) {
            #pragma unroll
            for (int n = 0; n < 2; ++n) {
                acc[m][n] = mfma16(AH[m], BH[n], acc[m][n]);
                acc[m][n] = mfma16(AL[m], BH[n], acc[m][n]);
                acc[m][n] = mfma16(AH[m], BL[n], acc[m][n]);
            }
        }
    };

    // Prologue: stage steps 0 and 1; wait for step 0 (leave step 1 in flight).
    stage(0, 0);
    stage(1, 1);
    if (tid < 128) asm volatile("s_waitcnt vmcnt(6)" ::: "memory");
    else           asm volatile("s_waitcnt vmcnt(5)" ::: "memory");
    __builtin_amdgcn_s_barrier();

    for (int k = 0; k < NSTEP; ++k) {
        const int nb = k + 2;
        if (nb < NSTEP) stage(nb % 3, nb);
        compute(k % 3);
        if (k + 1 < NSTEP) {
            if (nb < NSTEP) {
                if (tid < 128) asm volatile("s_waitcnt vmcnt(6)" ::: "memory");
                else           asm volatile("s_waitcnt vmcnt(5)" ::: "memory");
            } else {
                asm volatile("s_waitcnt vmcnt(0)" ::: "memory");
            }
            __builtin_amdgcn_s_barrier();
        }
    }

    #pragma unroll
    for (int m = 0; m < 3; ++m) {
        #pragma unroll
        for (int n = 0; n < 2; ++n) {
            int o = nbase + wid * 32 + n * 16 + r;
            float bv = bias[o];
            #pragma unroll
            for (int j = 0; j < 4; ++j) {
                int px = m * 16 + q * 4 + j;
                int xx = x0 + px;
                float v = acc[m][n][j] + bv;
                if (RELU) v = fmaxf(v, 0.f);
                if (MODE == 0) {
                    size_t P = (size_t)b * PP + (size_t)(y + 1) * 98 + xx + 1;
                    unsigned short h, l; split2(v, h, l);
                    ((unsigned short*)outv)[P * 2 * COUTP + o] = h;
                    ((unsigned short*)outv)[P * 2 * COUTP + COUTP + o] = l;
                } else if (MODE == 1) {
                    if (o < OMC)
                        ((unsigned short*)outv)[((size_t)b * HW + y * 96 + xx) * OMC + o] = f2bf(v);
                } else {
                    ((float*)outv)[((size_t)b * 128 + o) * HW + y * 96 + xx] = v;
                }
            }
        }
    }
}

// ---------------------------------------------------------------------------
// Deformable conv v2, weight-amortized: 32 px/block, 256 threads, 576 blocks
// (XCD-chunked 8x72) -> per-dispatch weight L2 stream halves (340 MB vs
// 680 MB), and each kp's 8 weight loads feed 16 MFMAs (2 m-frags).
// K split in halves; s_v[32][584] reused across halves (37 KB) + s_om
// [32][216] (13.8 KB) = 50 KB -> 3 blocks/CU. Flow per half: gather ->
// barrier -> Phase C (setprio'd) -> barrier. Unit order 0..35 preserved ->
// bit-identical output.
__global__ __launch_bounds__(256, 3) void deform_mfma(
    const unsigned short* __restrict__ xb,   // [NPIX][128] bf16 NHWC (R1)
    const unsigned short* __restrict__ omf,  // [NPIX][216] bf16
    const unsigned short* __restrict__ wpk,  // [2][128][1152] gk-major
    const float* __restrict__ bias,          // [128]
    unsigned short* __restrict__ cat)        // [2][98][98][512]
{
    __shared__ __align__(16) unsigned short s_v[32][584];   // half-K, +8 pad
    __shared__ __align__(16) unsigned short s_om[32][216];

    int tid = threadIdx.x;
    int bid = blockIdx.x;
    int swzb = (bid & 7) * 72 + (bid >> 3);   // XCD-chunked (576 = 8*72)
    int pix0 = swzb * 32;
    int b = pix0 / HW;

    // Stage om rows (32 px x 432B) into LDS, coalesced 16B chunks.
    for (int it = tid; it < 864; it += 256) {
        int p = it / 27, j = it - p * 27;
        *(ushort8x*)&s_om[p][j * 8] =
            *(const ushort8x*)&omf[(size_t)(pix0 + p) * OMC + j * 8];
    }
    __syncthreads();

    int wid = tid >> 6, lane = tid & 63;
    int r = lane & 15, q = lane >> 4;
    int n0 = wid * 32;
    f32x4 acc[2][2] = {};                    // [m-frag][n-frag]
    const unsigned short* wb = wpk + (size_t)(n0 + r) * 1152 + q * 8;

    #pragma unroll
    for (int hf = 0; hf < 2; ++hf) {
        // ---- gather half hf: 32 px x 36 gk = 1152 items ----
        for (int e = tid; e < 1152; e += 256) {
            int p = e & 31, gkl = e >> 5;
            int gk = hf * 36 + gkl;
            int pix = pix0 + p;
            int rem = pix % HW;
            int hh = rem / 96, ww = rem % 96;
            int g = gk / 9, k = gk - g * 9;
            const unsigned short* op = &s_om[p][0];
            float dy = bf2f(op[g * 18 + 2 * k]);
            float dx = bf2f(op[g * 18 + 2 * k + 1]);
            float mr = bf2f(op[144 + g * 9 + k]);
            float m = 1.f / (1.f + __expf(-mr));
            float py = dy + (float)(k / 3) + (float)hh - 1.f;
            float px = dx + (float)(k % 3) + (float)ww - 1.f;
            float fy = floorf(py), fx = floorf(px);
            int y0 = (int)fy, x0 = (int)fx;
            float ly = py - fy, lx = px - fx;
            float cw[4] = {(1.f - ly) * (1.f - lx), (1.f - ly) * lx,
                           ly * (1.f - lx), ly * lx};
            ushort8x cv0[4], cv1[4];
            #pragma unroll
            for (int j = 0; j < 4; ++j) {
                int yy = y0 + (j >> 1), xx = x0 + (j & 1);
                bool valid = ((unsigned)yy < 96u) && ((unsigned)xx < 96u);
                int yc = min(max(yy, 0), 95), xc = min(max(xx, 0), 95);
                const unsigned short* cp =
                    xb + ((size_t)(b * HW + yc * 96 + xc)) * 128 + g * 16;
                cv0[j] = *(const ushort8x*)cp;
                cv1[j] = *(const ushort8x*)(cp + 8);
                cw[j] = valid ? cw[j] * m : 0.f;
            }
            ushort8x o0, o1;
            #pragma unroll
            for (int i = 0; i < 8; ++i) {
                float v0 = cw[0] * bf2f(cv0[0][i]) + cw[1] * bf2f(cv0[1][i])
                         + cw[2] * bf2f(cv0[2][i]) + cw[3] * bf2f(cv0[3][i]);
                float v1 = cw[0] * bf2f(cv1[0][i]) + cw[1] * bf2f(cv1[1][i])
                         + cw[2] * bf2f(cv1[2][i]) + cw[3] * bf2f(cv1[3][i]);
                o0[i] = f2bf(v0);
                o1[i] = f2bf(v1);
            }
            *(ushort8x*)&s_v[p][gkl * 16    ] = o0;
            *(ushort8x*)&s_v[p][gkl * 16 + 8] = o1;
        }
        __syncthreads();

        // ---- Phase C half hf: units hf*18 .. hf*18+17 ----
        __builtin_amdgcn_s_setprio(1);
        #pragma unroll
        for (int kpl = 0; kpl < 9; ++kpl) {
            const int k0 = hf * 18 + kpl * 2, k1 = k0 + 1;
            short8x w00 = *(const short8x*)(wb + k0 * 32);
            short8x w10 = *(const short8x*)(wb + (size_t)16 * 1152 + k0 * 32);
            short8x l00 = *(const short8x*)(wb + 147456 + k0 * 32);
            short8x l10 = *(const short8x*)(wb + 147456 + (size_t)16 * 1152 + k0 * 32);
            short8x w01 = *(const short8x*)(wb + k1 * 32);
            short8x w11 = *(const short8x*)(wb + (size_t)16 * 1152 + k1 * 32);
            short8x l01 = *(const short8x*)(wb + 147456 + k1 * 32);
            short8x l11 = *(const short8x*)(wb + 147456 + (size_t)16 * 1152 + k1 * 32);
            #pragma unroll
            for (int m = 0; m < 2; ++m) {
                short8x a0 = *(const short8x*)&s_v[m * 16 + r][kpl * 64 + q * 8];
                short8x a1 = *(const short8x*)&s_v[m * 16 + r][kpl * 64 + 32 + q * 8];
                acc[m][0] = mfma16(a0, w00, acc[m][0]);
                acc[m][1] = mfma16(a0, w10, acc[m][1]);
                acc[m][0] = mfma16(a0, l00, acc[m][0]);
                acc[m][1] = mfma16(a0, l10, acc[m][1]);
                acc[m][0] = mfma16(a1, w01, acc[m][0]);
                acc[m][1] = mfma16(a1, w11, acc[m][1]);
                acc[m][0] = mfma16(a1, l01, acc[m][0]);
                acc[m][1] = mfma16(a1, l11, acc[m][1]);
            }
        }
        __builtin_amdgcn_s_setprio(0);
        if (hf == 0) __syncthreads();   // s_v reads done before next gather
    }

    #pragma unroll
    for (int m = 0; m < 2; ++m) {
        #pragma unroll
        for (int ni = 0; ni < 2; ++ni) {
            int o = n0 + ni * 16 + r;
            float bv = bias[o];
            #pragma unroll
            for (int j = 0; j < 4; ++j) {
                int pixel = pix0 + m * 16 + q * 4 + j;
                int bb = pixel / HW, rm = pixel % HW;
                int yy = rm / 96, xx = rm % 96;
                size_t P = (size_t)bb * PP + (size_t)(yy + 1) * 98 + xx + 1;
                float v = fmaxf(acc[m][ni][j] + bv, 0.f);
                unsigned short h, l;
                split2(v, h, l);
                cat[P * 512 + o] = h;
                cat[P * 512 + 256 + o] = l;
            }
        }
    }
}

// ---------------------------------------------------------------------------
extern "C" void kernel_launch(void* const* d_in, const int* in_sizes, int n_in,
                              void* d_out, int out_size, void* d_ws, size_t ws_size,
                              hipStream_t stream) {
    const float* R1    = (const float*)d_in[0];
    const float* Q0    = (const float*)d_in[1];
    const float* w1    = (const float*)d_in[2];
    const float* b1    = (const float*)d_in[3];
    const float* w2    = (const float*)d_in[4];
    const float* b2    = (const float*)d_in[5];
    const float* w_om  = (const float*)d_in[6];
    const float* b_om  = (const float*)d_in[7];
    const float* w_dcn = (const float*)d_in[8];
    const float* b_dcn = (const float*)d_in[9];
    const float* w_rq  = (const float*)d_in[10];
    const float* b_rq  = (const float*)d_in[11];
    float* outp = (float*)d_out;

    // Arena ~48 MiB (R8 layout). Padded activations [2][98][98][C].
    char* w = (char*)d_ws;
    unsigned short* r1b   = (unsigned short*)w; w += (size_t)NPIX * 128 * 2;      // 4.72 MB
    unsigned short* diffb = (unsigned short*)w; w += (size_t)2 * PP * 256 * 2;    // 9.83 MB (also t2)
    unsigned short* t1    = (unsigned short*)w; w += (size_t)2 * PP * 256 * 2;    // 9.83 MB (also omf)
    unsigned short* catb  = (unsigned short*)w; w += (size_t)2 * PP * 512 * 2;    // 19.67 MB
    unsigned short* p1    = (unsigned short*)w; w += 2 * 147456 * 2;
    unsigned short* p2    = (unsigned short*)w; w += 2 * 147456 * 2;
    unsigned short* pdcn  = (unsigned short*)w; w += 2 * 147456 * 2;
    unsigned short* pom   = (unsigned short*)w; w += 2 * 294912 * 2;
    unsigned short* prq   = (unsigned short*)w; w += 2 * 294912 * 2;
    float*          bomp  = (float*)w;          w += 256 * 4;
    unsigned short* t2    = diffb;   // diff dead after conv1
    unsigned short* omf   = t1;      // t1 dead after conv2; bf16 [NPIX][216]

    zero_borders<<<388, 256, 0, stream>>>(diffb, t1, catb);
    prep_acts<<<288, 256, 0, stream>>>(R1, Q0, r1b, diffb, catb);
    prep_w<<<1152, 256, 0, stream>>>(w1, w2, w_om, b_om, w_rq, w_dcn,
                                     p1, p2, pom, prq, pdcn, bomp);

    conv_mfma<128, 128, 0, true ><<<dim3(384, 1), 256, 0, stream>>>(diffb, p1, b1, t1);
    conv_mfma<128, 128, 0, true ><<<dim3(384, 1), 256, 0, stream>>>(t1,    p2, b2, t2);
    conv_mfma<128, 256, 1, false><<<dim3(384, 2), 256, 0, stream>>>(t2,   pom, bomp, omf);

    deform_mfma<<<576, 256, 0, stream>>>(r1b, omf, pdcn, b_dcn, catb);

    conv_mfma<256, 128, 2, true ><<<dim3(384, 1), 256, 0, stream>>>(catb, prq, b_rq, outp);
}

// Round 25
// 360.670 us; speedup vs baseline: 1.0756x; 1.0009x over previous
//
#include <hip/hip_runtime.h>

#define HH 96
#define WW 96
#define HW 9216
#define NPIX 18432      // B*H*W, B=2
#define OMC 216
#define PP 9604         // 98*98 padded image

typedef __attribute__((ext_vector_type(8))) short short8x;       // MFMA bf16 frag
typedef __attribute__((ext_vector_type(8))) unsigned short ushort8x;
typedef __attribute__((ext_vector_type(4))) float f32x4;

__device__ __forceinline__ f32x4 mfma16(short8x a, short8x b, f32x4 c) {
    return __builtin_amdgcn_mfma_f32_16x16x32_bf16(a, b, c, 0, 0, 0);
}
__device__ __forceinline__ unsigned short f2bf(float f) {
    unsigned int u = __float_as_uint(f);
    u = (u + 0x7FFFu + ((u >> 16) & 1u)) >> 16;   // RNE (finite values)
    return (unsigned short)u;
}
__device__ __forceinline__ float bf2f(unsigned short b) {
    return __uint_as_float((unsigned int)b << 16);
}
__device__ __forceinline__ void split2(float v, unsigned short& h, unsigned short& l) {
    h = f2bf(v);
    l = f2bf(v - bf2f(h));
}
__device__ __forceinline__ void gld_lds16(const unsigned short* src, unsigned short* dst) {
    __builtin_amdgcn_global_load_lds(
        (const __attribute__((address_space(1))) unsigned int*)src,
        (__attribute__((address_space(3))) unsigned int*)dst, 16, 0, 0);
}

// ---------------------------------------------------------------------------
// Zero the 1-px border of the padded activation buffers. Fully parallel:
// one 16B store per thread (776 border px x 128 stores = 99328 items).
__global__ __launch_bounds__(256) void zero_borders(
    unsigned short* __restrict__ diffb,   // [2][98][98][256]
    unsigned short* __restrict__ t1,      // [2][98][98][256]
    unsigned short* __restrict__ catb)    // [2][98][98][512]
{
    int idx = blockIdx.x * 256 + threadIdx.x;
    if (idx >= 99328) return;
    int i = idx >> 7, sub = idx & 127;
    int b = i / 388, r = i % 388;
    int y, x;
    if      (r < 98)  { y = 0;           x = r; }
    else if (r < 196) { y = 97;          x = r - 98; }
    else if (r < 292) { y = r - 196 + 1; x = 0; }
    else              { y = r - 292 + 1; x = 97; }
    size_t P = (size_t)b * PP + (size_t)y * 98 + x;
    ushort8x z = {};
    if (sub < 32)      *(ushort8x*)&diffb[P * 256 + sub * 8] = z;
    else if (sub < 64) *(ushort8x*)&t1[P * 256 + (sub - 32) * 8] = z;
    else               *(ushort8x*)&catb[P * 512 + (sub - 64) * 8] = z;
}

// ---------------------------------------------------------------------------
// NCHW fp32 -> r1b (bf16 NHWC, gather src), diff=R1-Q0 (hi/lo bf16, padded),
// Q0 -> padded cat channels (hi 128..255, lo 384..511). 64 pixels per block.
__global__ __launch_bounds__(256) void prep_acts(
    const float* __restrict__ R1, const float* __restrict__ Q0,
    unsigned short* __restrict__ r1b,    // [NPIX][128] bf16
    unsigned short* __restrict__ diffb,  // [2][98][98][256] hi|lo
    unsigned short* __restrict__ cat)    // [2][98][98][512]
{
    __shared__ float tR[128][64];
    __shared__ float tQ[128][64];
    int tid = threadIdx.x;
    int p0  = blockIdx.x * 64;
    int b   = p0 / HW;
    int rem0 = p0 % HW;

    for (int e = tid; e < 2048; e += 256) {          // 128 ch x 16 float4
        int c = e >> 4, j = e & 15;
        size_t base = ((size_t)(b * 128 + c)) * HW + rem0;
        *(float4*)&tR[c][j * 4] = *(const float4*)(R1 + base + j * 4);
        *(float4*)&tQ[c][j * 4] = *(const float4*)(Q0 + base + j * 4);
    }
    __syncthreads();

    int p = tid & 63, half = tid >> 6;   // half 0..3
    int c0 = half * 32;
    int pix = p0 + p;
    int rm = pix % HW, yy = rm / 96, xx = rm % 96;
    size_t P = (size_t)b * PP + (size_t)(yy + 1) * 98 + xx + 1;
    ushort8x rb[4], dh[4], dl[4], qh[4], ql[4];
    #pragma unroll
    for (int cc = 0; cc < 32; ++cc) {
        float r = tR[c0 + cc][p], q = tQ[c0 + cc][p];
        rb[cc >> 3][cc & 7] = f2bf(r);
        unsigned short h, l;
        split2(r - q, h, l); dh[cc >> 3][cc & 7] = h; dl[cc >> 3][cc & 7] = l;
        split2(q, h, l);     qh[cc >> 3][cc & 7] = h; ql[cc >> 3][cc & 7] = l;
    }
    #pragma unroll
    for (int i = 0; i < 4; ++i) {
        *(ushort8x*)&r1b[(size_t)pix * 128 + c0 + i * 8] = rb[i];
        *(ushort8x*)&diffb[P * 256 +       c0 + i * 8] = dh[i];
        *(ushort8x*)&diffb[P * 256 + 128 + c0 + i * 8] = dl[i];
        *(ushort8x*)&cat [P * 512 + 128 + c0 + i * 8] = qh[i];
        *(ushort8x*)&cat [P * 512 + 384 + c0 + i * 8] = ql[i];
    }
}

// ---------------------------------------------------------------------------
// Weight repack to bf16 hi/lo planes.
// p1/p2: [2][9][128][128]; pom: [2][9][256][128]; prq: [2][9][128][256]
// pdcn:  [2][128][1152], K-order = (g*9+t)*16 + (ci&15)  (gk-major)
__global__ __launch_bounds__(256) void prep_w(
    const float* __restrict__ w1, const float* __restrict__ w2,
    const float* __restrict__ wom, const float* __restrict__ bom,
    const float* __restrict__ wrq, const float* __restrict__ wdcn,
    unsigned short* __restrict__ p1, unsigned short* __restrict__ p2,
    unsigned short* __restrict__ pom, unsigned short* __restrict__ prq,
    unsigned short* __restrict__ pdcn, float* __restrict__ bomp)
{
    int idx = blockIdx.x * 256 + threadIdx.x;
    unsigned short h, l;
    if (idx < 147456) {                   // 9*128*128
        int t = idx / 16384, o = (idx >> 7) & 127, ci = idx & 127;
        int src = (o * 128 + ci) * 9 + t;
        split2(w1[src], h, l);  p1[idx] = h;  p1[idx + 147456] = l;
        split2(w2[src], h, l);  p2[idx] = h;  p2[idx + 147456] = l;
        int dd = o * 1152 + ((ci >> 4) * 9 + t) * 16 + (ci & 15);
        split2(wdcn[src], h, l); pdcn[dd] = h; pdcn[dd + 147456] = l;
    }
    if (idx < 294912) {
        { // om
            int t = idx / 32768, o = (idx >> 7) & 255, ci = idx & 127;
            float v = (o < OMC) ? wom[(o * 128 + ci) * 9 + t] : 0.f;
            split2(v, h, l); pom[idx] = h; pom[idx + 294912] = l;
        }
        { // rq
            int t = idx / 32768, o = (idx >> 8) & 127, ci = idx & 255;
            split2(wrq[(o * 256 + ci) * 9 + t], h, l);
            prq[idx] = h; prq[idx + 294912] = l;
        }
    }
    if (idx < 256) bomp[idx] = (idx < OMC) ? bom[idx] : 0.f;
}

// ---------------------------------------------------------------------------
// Shift-GEMM 3x3 conv on zero-padded NHWC hi/lo bf16, MFMA 16x16x32,
// 3-product compensation. Block = 48 px (half row) x 128 outs, 4 waves.
// 3-buffer LDS, stage 2 K-steps ahead, raw s_barrier with counted
// s_waitcnt vmcnt(L) (w0/w1: 6 loads/step -> vmcnt(6); w2/w3: 5 -> vmcnt(5)).
template<int CIN, int COUTP, int MODE, bool RELU>
__global__ __launch_bounds__(256, 2) void conv_mfma(
    const unsigned short* __restrict__ in,   // padded [2][98][98][2*CIN]
    const unsigned short* __restrict__ wpk,  // [2][9][COUTP][CIN]
    const float* __restrict__ bias,          // [COUTP]
    void* __restrict__ outv)
{
    constexpr int NKC = CIN / 32;
    constexpr int NSTEP = 9 * NKC;
    const size_t WPLANE = (size_t)9 * COUTP * CIN;

    __shared__ __align__(16) unsigned short s_buf[3][3072 + 8192];

    int tid = threadIdx.x;
    int wid = tid >> 6, lane = tid & 63;
    int r = lane & 15, q = lane >> 4;
    int bid = blockIdx.x;
    int swz = (bid & 7) * 48 + (bid >> 3);   // XCD-chunked (384 = 8*48)
    int rowid = swz >> 1, half = swz & 1;
    int b = rowid / 96, y = rowid % 96;
    int x0 = half * 48;
    int nbase = blockIdx.y * 128;

    auto stage = [&](int buf, int step) {
        int t = step / NKC, kc = step - t * NKC;
        int dy = t / 3 - 1, dx = t % 3 - 1;
        unsigned short* sb = &s_buf[buf][0];
        {
            int j = tid;
            int m = j >> 7, pl = (j >> 6) & 1, L = j & 63;
            int px = m * 16 + (L & 15), qd = L >> 4;
            const unsigned short* src = in +
                ((size_t)b * PP + (size_t)(y + 1 + dy) * 98 + (x0 + 1 + dx + px)) * (2 * CIN)
                + pl * CIN + kc * 32 + qd * 8;
            gld_lds16(src, sb + (size_t)(wid * 64) * 8);
        }
        if (tid < 128) {
            int j = 256 + tid;
            int m = j >> 7, pl = (j >> 6) & 1, L = j & 63;
            int px = m * 16 + (L & 15), qd = L >> 4;
            const unsigned short* src = in +
                ((size_t)b * PP + (size_t)(y + 1 + dy) * 98 + (x0 + 1 + dx + px)) * (2 * CIN)
                + pl * CIN + kc * 32 + qd * 8;
            gld_lds16(src, sb + (size_t)(256 + wid * 64) * 8);
        }
        const unsigned short* wbase = wpk + ((size_t)t * COUTP + nbase) * CIN + kc * 32;
        #pragma unroll
        for (int c = 0; c < 4; ++c) {
            int j = c * 256 + tid;
            int ni = (j >> 7) & 1, pl = (j >> 6) & 1, L = j & 63;
            int rr = L & 15, qq = L >> 4;
            const unsigned short* src = wbase + (size_t)pl * WPLANE
                + (size_t)(c * 32 + ni * 16 + rr) * CIN + qq * 8;
            gld_lds16(src, sb + 3072 + (size_t)(c * 256 + wid * 64) * 8);
        }
    };

    f32x4 acc[3][2] = {};

    auto compute = [&](int buf) {
        const unsigned short* sb = &s_buf[buf][0];
        short8x AH[3], AL[3], BH[2], BL[2];
        #pragma unroll
        for (int m = 0; m < 3; ++m) {
            AH[m] = *(const short8x*)(sb + m * 1024 + lane * 8);
            AL[m] = *(const short8x*)(sb + m * 1024 + 512 + lane * 8);
        }
        #pragma unroll
        for (int n = 0; n < 2; ++n) {
            BH[n] = *(const short8x*)(sb + 3072 + wid * 2048 + n * 1024 + lane * 8);
            BL[n] = *(const short8x*)(sb + 3072 + wid * 2048 + n * 1024 + 512 + lane * 8);
        }
        #pragma unroll
        for (int m = 0; m < 3; ++m) {
            #pragma unroll
            for (int n = 0; n < 2; ++n) {
                acc[m][n] = mfma16(AH[m], BH[n], acc[m][n]);
                acc[m][n] = mfma16(AL[m], BH[n], acc[m][n]);
                acc[m][n] = mfma16(AH[m], BL[n], acc[m][n]);
            }
        }
    };

    // Prologue: stage steps 0 and 1; wait for step 0 (leave step 1 in flight).
    stage(0, 0);
    stage(1, 1);
    if (tid < 128) asm volatile("s_waitcnt vmcnt(6)" ::: "memory");
    else           asm volatile("s_waitcnt vmcnt(5)" ::: "memory");
    __builtin_amdgcn_s_barrier();

    for (int k = 0; k < NSTEP; ++k) {
        const int nb = k + 2;
        if (nb < NSTEP) stage(nb % 3, nb);
        compute(k % 3);
        if (k + 1 < NSTEP) {
            if (nb < NSTEP) {
                if (tid < 128) asm volatile("s_waitcnt vmcnt(6)" ::: "memory");
                else           asm volatile("s_waitcnt vmcnt(5)" ::: "memory");
            } else {
                asm volatile("s_waitcnt vmcnt(0)" ::: "memory");
            }
            __builtin_amdgcn_s_barrier();
        }
    }

    #pragma unroll
    for (int m = 0; m < 3; ++m) {
        #pragma unroll
        for (int n = 0; n < 2; ++n) {
            int o = nbase + wid * 32 + n * 16 + r;
            float bv = bias[o];
            #pragma unroll
            for (int j = 0; j < 4; ++j) {
                int px = m * 16 + q * 4 + j;
                int xx = x0 + px;
                float v = acc[m][n][j] + bv;
                if (RELU) v = fmaxf(v, 0.f);
                if (MODE == 0) {
                    size_t P = (size_t)b * PP + (size_t)(y + 1) * 98 + xx + 1;
                    unsigned short h, l; split2(v, h, l);
                    ((unsigned short*)outv)[P * 2 * COUTP + o] = h;
                    ((unsigned short*)outv)[P * 2 * COUTP + COUTP + o] = l;
                } else if (MODE == 1) {
                    if (o < OMC)
                        ((unsigned short*)outv)[((size_t)b * HW + y * 96 + xx) * OMC + o] = f2bf(v);
                } else {
                    ((float*)outv)[((size_t)b * 128 + o) * HW + y * 96 + xx] = v;
                }
            }
        }
    }
}

// ---------------------------------------------------------------------------
// Deformable conv v2, weight-amortized: 32 px/block, 256 threads, 576 blocks
// (XCD-chunked 8x72) -> per-dispatch weight L2 stream halves (340 MB vs
// 680 MB), and each kp's 8 weight loads feed 16 MFMAs (2 m-frags).
// K split in halves; s_v[32][584] reused across halves (37 KB) + s_om
// [32][216] (13.8 KB) = 50 KB -> 3 blocks/CU. Flow per half: gather ->
// barrier -> Phase C (setprio'd) -> barrier. Unit order 0..35 preserved ->
// bit-identical output.
__global__ __launch_bounds__(256, 3) void deform_mfma(
    const unsigned short* __restrict__ xb,   // [NPIX][128] bf16 NHWC (R1)
    const unsigned short* __restrict__ omf,  // [NPIX][216] bf16
    const unsigned short* __restrict__ wpk,  // [2][128][1152] gk-major
    const float* __restrict__ bias,          // [128]
    unsigned short* __restrict__ cat)        // [2][98][98][512]
{
    __shared__ __align__(16) unsigned short s_v[32][584];   // half-K, +8 pad
    __shared__ __align__(16) unsigned short s_om[32][216];

    int tid = threadIdx.x;
    int bid = blockIdx.x;
    int swzb = (bid & 7) * 72 + (bid >> 3);   // XCD-chunked (576 = 8*72)
    int pix0 = swzb * 32;
    int b = pix0 / HW;

    // Stage om rows (32 px x 432B) into LDS, coalesced 16B chunks.
    for (int it = tid; it < 864; it += 256) {
        int p = it / 27, j = it - p * 27;
        *(ushort8x*)&s_om[p][j * 8] =
            *(const ushort8x*)&omf[(size_t)(pix0 + p) * OMC + j * 8];
    }
    __syncthreads();

    int wid = tid >> 6, lane = tid & 63;
    int r = lane & 15, q = lane >> 4;
    int n0 = wid * 32;
    f32x4 acc[2][2] = {};                    // [m-frag][n-frag]
    const unsigned short* wb = wpk + (size_t)(n0 + r) * 1152 + q * 8;

    #pragma unroll
    for (int hf = 0; hf < 2; ++hf) {
        // ---- gather half hf: 32 px x 36 gk = 1152 items ----
        for (int e = tid; e < 1152; e += 256) {
            int p = e & 31, gkl = e >> 5;
            int gk = hf * 36 + gkl;
            int pix = pix0 + p;
            int rem = pix % HW;
            int hh = rem / 96, ww = rem % 96;
            int g = gk / 9, k = gk - g * 9;
            const unsigned short* op = &s_om[p][0];
            float dy = bf2f(op[g * 18 + 2 * k]);
            float dx = bf2f(op[g * 18 + 2 * k + 1]);
            float mr = bf2f(op[144 + g * 9 + k]);
            float m = 1.f / (1.f + __expf(-mr));
            float py = dy + (float)(k / 3) + (float)hh - 1.f;
            float px = dx + (float)(k % 3) + (float)ww - 1.f;
            float fy = floorf(py), fx = floorf(px);
            int y0 = (int)fy, x0 = (int)fx;
            float ly = py - fy, lx = px - fx;
            float cw[4] = {(1.f - ly) * (1.f - lx), (1.f - ly) * lx,
                           ly * (1.f - lx), ly * lx};
            ushort8x cv0[4], cv1[4];
            #pragma unroll
            for (int j = 0; j < 4; ++j) {
                int yy = y0 + (j >> 1), xx = x0 + (j & 1);
                bool valid = ((unsigned)yy < 96u) && ((unsigned)xx < 96u);
                int yc = min(max(yy, 0), 95), xc = min(max(xx, 0), 95);
                const unsigned short* cp =
                    xb + ((size_t)(b * HW + yc * 96 + xc)) * 128 + g * 16;
                cv0[j] = *(const ushort8x*)cp;
                cv1[j] = *(const ushort8x*)(cp + 8);
                cw[j] = valid ? cw[j] * m : 0.f;
            }
            ushort8x o0, o1;
            #pragma unroll
            for (int i = 0; i < 8; ++i) {
                float v0 = cw[0] * bf2f(cv0[0][i]) + cw[1] * bf2f(cv0[1][i])
                         + cw[2] * bf2f(cv0[2][i]) + cw[3] * bf2f(cv0[3][i]);
                float v1 = cw[0] * bf2f(cv1[0][i]) + cw[1] * bf2f(cv1[1][i])
                         + cw[2] * bf2f(cv1[2][i]) + cw[3] * bf2f(cv1[3][i]);
                o0[i] = f2bf(v0);
                o1[i] = f2bf(v1);
            }
            *(ushort8x*)&s_v[p][gkl * 16    ] = o0;
            *(ushort8x*)&s_v[p][gkl * 16 + 8] = o1;
        }
        __syncthreads();

        // ---- Phase C half hf: units hf*18 .. hf*18+17 ----
        __builtin_amdgcn_s_setprio(1);
        #pragma unroll
        for (int kpl = 0; kpl < 9; ++kpl) {
            const int k0 = hf * 18 + kpl * 2, k1 = k0 + 1;
            short8x w00 = *(const short8x*)(wb + k0 * 32);
            short8x w10 = *(const short8x*)(wb + (size_t)16 * 1152 + k0 * 32);
            short8x l00 = *(const short8x*)(wb + 147456 + k0 * 32);
            short8x l10 = *(const short8x*)(wb + 147456 + (size_t)16 * 1152 + k0 * 32);
            short8x w01 = *(const short8x*)(wb + k1 * 32);
            short8x w11 = *(const short8x*)(wb + (size_t)16 * 1152 + k1 * 32);
            short8x l01 = *(const short8x*)(wb + 147456 + k1 * 32);
            short8x l11 = *(const short8x*)(wb + 147456 + (size_t)16 * 1152 + k1 * 32);
            #pragma unroll
            for (int m = 0; m < 2; ++m) {
                short8x a0 = *(const short8x*)&s_v[m * 16 + r][kpl * 64 + q * 8];
                short8x a1 = *(const short8x*)&s_v[m * 16 + r][kpl * 64 + 32 + q * 8];
                acc[m][0] = mfma16(a0, w00, acc[m][0]);
                acc[m][1] = mfma16(a0, w10, acc[m][1]);
                acc[m][0] = mfma16(a0, l00, acc[m][0]);
                acc[m][1] = mfma16(a0, l10, acc[m][1]);
                acc[m][0] = mfma16(a1, w01, acc[m][0]);
                acc[m][1] = mfma16(a1, w11, acc[m][1]);
                acc[m][0] = mfma16(a1, l01, acc[m][0]);
                acc[m][1] = mfma16(a1, l11, acc[m][1]);
            }
        }
        __builtin_amdgcn_s_setprio(0);
        if (hf == 0) __syncthreads();   // s_v reads done before next gather
    }

    #pragma unroll
    for (int m = 0; m < 2; ++m) {
        #pragma unroll
        for (int ni = 0; ni < 2; ++ni) {
            int o = n0 + ni * 16 + r;
            float bv = bias[o];
            #pragma unroll
            for (int j = 0; j < 4; ++j) {
                int pixel = pix0 + m * 16 + q * 4 + j;
                int bb = pixel / HW, rm = pixel % HW;
                int yy = rm / 96, xx = rm % 96;
                size_t P = (size_t)bb * PP + (size_t)(yy + 1) * 98 + xx + 1;
                float v = fmaxf(acc[m][ni][j] + bv, 0.f);
                unsigned short h, l;
                split2(v, h, l);
                cat[P * 512 + o] = h;
                cat[P * 512 + 256 + o] = l;
            }
        }
    }
}

// ---------------------------------------------------------------------------
extern "C" void kernel_launch(void* const* d_in, const int* in_sizes, int n_in,
                              void* d_out, int out_size, void* d_ws, size_t ws_size,
                              hipStream_t stream) {
    const float* R1    = (const float*)d_in[0];
    const float* Q0    = (const float*)d_in[1];
    const float* w1    = (const float*)d_in[2];
    const float* b1    = (const float*)d_in[3];
    const float* w2    = (const float*)d_in[4];
    const float* b2    = (const float*)d_in[5];
    const float* w_om  = (const float*)d_in[6];
    const float* b_om  = (const float*)d_in[7];
    const float* w_dcn = (const float*)d_in[8];
    const float* b_dcn = (const float*)d_in[9];
    const float* w_rq  = (const float*)d_in[10];
    const float* b_rq  = (const float*)d_in[11];
    float* outp = (float*)d_out;

    // Arena ~48 MiB (R8 layout). Padded activations [2][98][98][C].
    char* w = (char*)d_ws;
    unsigned short* r1b   = (unsigned short*)w; w += (size_t)NPIX * 128 * 2;      // 4.72 MB
    unsigned short* diffb = (unsigned short*)w; w += (size_t)2 * PP * 256 * 2;    // 9.83 MB (also t2)
    unsigned short* t1    = (unsigned short*)w; w += (size_t)2 * PP * 256 * 2;    // 9.83 MB (also omf)
    unsigned short* catb  = (unsigned short*)w; w += (size_t)2 * PP * 512 * 2;    // 19.67 MB
    unsigned short* p1    = (unsigned short*)w; w += 2 * 147456 * 2;
    unsigned short* p2    = (unsigned short*)w; w += 2 * 147456 * 2;
    unsigned short* pdcn  = (unsigned short*)w; w += 2 * 147456 * 2;
    unsigned short* pom   = (unsigned short*)w; w += 2 * 294912 * 2;
    unsigned short* prq   = (unsigned short*)w; w += 2 * 294912 * 2;
    float*          bomp  = (float*)w;          w += 256 * 4;
    unsigned short* t2    = diffb;   // diff dead after conv1
    unsigned short* omf   = t1;      // t1 dead after conv2; bf16 [NPIX][216]

    zero_borders<<<388, 256, 0, stream>>>(diffb, t1, catb);
    prep_acts<<<288, 256, 0, stream>>>(R1, Q0, r1b, diffb, catb);
    prep_w<<<1152, 256, 0, stream>>>(w1, w2, w_om, b_om, w_rq, w_dcn,
                                     p1, p2, pom, prq, pdcn, bomp);

    conv_mfma<128, 128, 0, true ><<<dim3(384, 1), 256, 0, stream>>>(diffb, p1, b1, t1);
    conv_mfma<128, 128, 0, true ><<<dim3(384, 1), 256, 0, stream>>>(t1,    p2, b2, t2);
    conv_mfma<128, 256, 1, false><<<dim3(384, 2), 256, 0, stream>>>(t2,   pom, bomp, omf);

    deform_mfma<<<576, 256, 0, stream>>>(r1b, omf, pdcn, b_dcn, catb);

    conv_mfma<256, 128, 2, true ><<<dim3(384, 1), 256, 0, stream>>>(catb, prq, b_rq, outp);
}